// Round 15
// baseline (1212.195 us; speedup 1.0000x reference)
//
#include <hip/hip_runtime.h>

#define BATCH 2
#define NH    16
#define SEQ   2048
#define DH    64
#define KT    32
#define KHALF (SEQ / 2)
#define CH    128              // chunk columns (contiguity unit = 512B/row)
#define NCH   (KHALF / CH)     // 8 chunks per k-half
#define NSUB  (CH / KT)        // 4 MFMA sub-tiles per chunk
#define SSTR  132              // score LDS row stride in dwords (128+4 pad)
#define PSTR  136              // pv LDS row stride in bf16 elems

typedef __attribute__((ext_vector_type(8))) short          bf16x8;
typedef __attribute__((ext_vector_type(4))) float          f32x4;
typedef __attribute__((ext_vector_type(2))) unsigned int   u32x2;
typedef __attribute__((ext_vector_type(4))) int            i32x4;

__device__ __forceinline__ unsigned short f2bf(float f) {   // RNE (Q only)
    union { float f; unsigned int i; } c;
    c.f = f;
    unsigned int x = c.i;
    x += 0x7fffu + ((x >> 16) & 1u);
    return (unsigned short)(x >> 16);
}
__device__ __forceinline__ unsigned int pkt(float lo, float hi) {   // trunc bf16 pair
    union { float f; unsigned int u; } a, b;
    a.f = lo; b.f = hi;
    return (b.u & 0xFFFF0000u) | (a.u >> 16);
}

// ============ kernel 1: scores, LDS pivot + chunk-double-buffered bias/mask ============
template<bool ISBYTE>
__global__ __launch_bounds__(128, 2)
void sdpa_score(const float* __restrict__ qp,
                const float* __restrict__ kp,
                const void*  __restrict__ mp,
                const float* __restrict__ bp,
                float* __restrict__ attnp,
                float* __restrict__ lsump)
{
    __shared__ __align__(16) float S_lds[2][16 * SSTR];   // raw-score chunk per wave

    const int tid  = threadIdx.x;
    const int wid  = tid >> 6;          // k-half
    const int lane = tid & 63;
    const int l15  = lane & 15;         // q (fragment layout)
    const int g    = lane >> 4;
    const int cl   = lane & 31;         // consume: col-lane (16B granule)
    const int hi   = lane >> 5;         // consume: row parity

    const unsigned int* mw = (const unsigned int*)mp;
    if ((__any((int)(mw[lane & 31] > 1u)) != 0) != ISBYTE) return;

    const int bid  = blockIdx.x;
    const int orig = (bid & 7) * 512 + (bid >> 3);   // bijective XCD swizzle
    const int h    = orig >> 8;
    const int rem  = orig & 255;
    const int qt   = rem >> 1;
    const int b    = rem & 1;                        // b-pair adjacent -> bias L2 share
    const int bh   = b * NH + h;
    const int qbase = qt * 16;
    const int k0   = wid * KHALF;

    const float* kbh = kp + (size_t)bh * SEQ * DH;
    float* sw = &S_lds[wid][0];

    bf16x8 qf0, qf1;
    {
        const float* qb = qp + ((size_t)bh * SEQ + qbase + l15) * DH + g * 8;
        #pragma unroll
        for (int j = 0; j < 8; ++j) {
            qf0[j] = (short)f2bf(qb[j]      * 0.125f);
            qf1[j] = (short)f2bf(qb[32 + j] * 0.125f);
        }
    }

    struct KS { f32x4 k[2][4]; };
    auto load_k = [&](int tk, KS& R) {               // tk = sub-tile idx in k-half
        const int kb = k0 + tk * KT;
        #pragma unroll
        for (int mb = 0; mb < 2; ++mb) {
            const float* arow = kbh + (size_t)(kb + 16 * mb + l15) * DH + g * 8;
            R.k[mb][0] = *(const f32x4*)(arow);
            R.k[mb][1] = *(const f32x4*)(arow + 4);
            R.k[mb][2] = *(const f32x4*)(arow + 32);
            R.k[mb][3] = *(const f32x4*)(arow + 36);
        }
    };

    auto produce = [&](const KS& R, int ko) {        // ko = col offset in chunk
        #pragma unroll
        for (int mb = 0; mb < 2; ++mb) {
            union { bf16x8 v; unsigned int u[4]; } A0, A1;
            A0.u[0] = pkt(R.k[mb][0][0], R.k[mb][0][1]);
            A0.u[1] = pkt(R.k[mb][0][2], R.k[mb][0][3]);
            A0.u[2] = pkt(R.k[mb][1][0], R.k[mb][1][1]);
            A0.u[3] = pkt(R.k[mb][1][2], R.k[mb][1][3]);
            A1.u[0] = pkt(R.k[mb][2][0], R.k[mb][2][1]);
            A1.u[1] = pkt(R.k[mb][2][2], R.k[mb][2][3]);
            A1.u[2] = pkt(R.k[mb][3][0], R.k[mb][3][1]);
            A1.u[3] = pkt(R.k[mb][3][2], R.k[mb][3][3]);
            f32x4 c = (f32x4){0.f, 0.f, 0.f, 0.f};
            __builtin_amdgcn_s_setprio(1);
            c = __builtin_amdgcn_mfma_f32_16x16x32_bf16(A0.v, qf0, c, 0, 0, 0);
            c = __builtin_amdgcn_mfma_f32_16x16x32_bf16(A1.v, qf1, c, 0, 0, 0);
            __builtin_amdgcn_s_setprio(0);
            *(f32x4*)(sw + l15 * SSTR + ko + 16 * mb + 4 * g) = c;
        }
    };

    struct BiasT { f32x4 bias[8]; unsigned int m8[8]; i32x4 mi[8]; };
    auto load_bias = [&](int c, BiasT& B) {          // contiguous: 2 rows x 512B per instr
        const int colbase = k0 + c * CH;
        #pragma unroll
        for (int i = 0; i < 8; ++i) {
            const int row = qbase + 2 * i + hi;
            B.bias[i] = *(const f32x4*)(bp + ((size_t)h * SEQ + row) * SEQ + colbase + 4 * cl);
            if constexpr (ISBYTE)
                B.m8[i] = *(const unsigned int*)((const unsigned char*)mp +
                           ((size_t)b * SEQ + row) * SEQ + colbase + 4 * cl);
            else
                B.mi[i] = *(const i32x4*)((const int*)mp +
                           ((size_t)b * SEQ + row) * SEQ + colbase + 4 * cl);
        }
    };

    float rs[8];
    #pragma unroll
    for (int i = 0; i < 8; ++i) rs[i] = 0.0f;

    auto consume = [&](int c, const BiasT& B) {      // LDS raw + bias -> exp -> attn
        const int colbase = k0 + c * CH;
        #pragma unroll
        for (int i = 0; i < 8; ++i) {
            const int row = 2 * i + hi;
            f32x4 p = *(const f32x4*)(sw + row * SSTR + 4 * cl);
            f32x4 pa;
            #pragma unroll
            for (int j = 0; j < 4; ++j) {
                const float s = p[j] + B.bias[i][j];
                int m;
                if constexpr (ISBYTE) m = (int)((B.m8[i] >> (8 * j)) & 0xFFu);
                else                  m = B.mi[i][j];
                pa[j] = m ? 0.0f : __expf(s);
            }
            rs[i] += pa[0] + pa[1] + pa[2] + pa[3];   // lane-local; reduce deferred
            *(f32x4*)(attnp + ((size_t)bh * SEQ + qbase + row) * SEQ + colbase + 4 * cl) = pa;
        }
    };

    KS RA, RB;
    load_k(0, RA);
    load_k(1, RB);

    auto produce_chunk = [&](int c) {
        #pragma unroll
        for (int s = 0; s < NSUB; ++s) {
            const int tk = 4 * c + s;
            if ((s & 1) == 0) { produce(RA, s * KT); load_k((tk + 2) & 31, RA); }
            else              { produce(RB, s * KT); load_k((tk + 2) & 31, RB); }
        }
    };

    {
        BiasT BA, BB;
        load_bias(0, BA);                            // prologue
        for (int c = 0; c < NCH; c += 2) {
            load_bias(c + 1, BB);                    // issue next chunk's bias/mask early
            produce_chunk(c);
            consume(c, BA);                          // BA issued >= 1 full iter ago
            load_bias((c + 2) & (NCH - 1), BA);      // ring (last wraps harmlessly)
            produce_chunk(c + 1);
            consume(c + 1, BB);
        }
    }

    // deferred row-sum reduce: 5-level tree once per row, then 2 atomics/row total
    #pragma unroll
    for (int i = 0; i < 8; ++i) {
        float t = rs[i];
        t += __shfl_xor(t, 1, 64);
        t += __shfl_xor(t, 2, 64);
        t += __shfl_xor(t, 4, 64);
        t += __shfl_xor(t, 8, 64);
        t += __shfl_xor(t, 16, 64);
        rs[i] = t;
    }
    if (cl == 0) {
        #pragma unroll
        for (int i = 0; i < 8; ++i)
            atomicAdd(&lsump[(size_t)bh * SEQ + qbase + 2 * i + hi], rs[i]);
    }
}

// ============ kernel 2: normalize attn (contiguous R/W) + out = P_norm . V ============
__global__ __launch_bounds__(128, 2)
void sdpa_pv(const float* __restrict__ vp,
             float* __restrict__ attnp,
             const float* __restrict__ lsump,
             float* __restrict__ outp)
{
    __shared__ __align__(16) unsigned short P_lds[2][16 * PSTR];
    __shared__ float OA[16][65];

    const int tid  = threadIdx.x;
    const int wid  = tid >> 6;
    const int lane = tid & 63;
    const int l15  = lane & 15;
    const int g    = lane >> 4;
    const int cl   = lane & 31;
    const int hi   = lane >> 5;

    const int bid  = blockIdx.x;
    const int orig = (bid & 7) * 512 + (bid >> 3);
    const int bh   = orig >> 7;                      // 4 bh per XCD -> V fits L2
    const int qt   = orig & 127;
    const int qbase = qt * 16;
    const int k0   = wid * KHALF;

    float rv8[8];
    #pragma unroll
    for (int i = 0; i < 8; ++i)
        rv8[i] = 1.0f / lsump[(size_t)bh * SEQ + qbase + 2 * i + hi];

    const float* vbh = vp + (size_t)bh * SEQ * DH + (size_t)k0 * DH;
    unsigned short* pw = &P_lds[wid][0];

    f32x4 accO[4];
    #pragma unroll
    for (int i = 0; i < 4; ++i) accO[i] = (f32x4){0.f, 0.f, 0.f, 0.f};

    struct VS { float v[4][8]; };
    auto load_v = [&](int tk, VS& S) {
        const float* vb2 = vbh + (size_t)tk * KT * DH + 512 * g + l15;
        #pragma unroll
        for (int nb = 0; nb < 4; ++nb)
            #pragma unroll
            for (int j = 0; j < 8; ++j)
                S.v[nb][j] = vb2[j * 64 + 16 * nb];
    };

    auto load_av = [&](int c, f32x4* av) {
        #pragma unroll
        for (int i = 0; i < 8; ++i)
            av[i] = *(const f32x4*)(attnp + ((size_t)bh * SEQ + qbase + 2 * i + hi) * SEQ
                                    + k0 + c * CH + 4 * cl);
    };
    auto consume_av = [&](int c, const f32x4* av) {
        #pragma unroll
        for (int i = 0; i < 8; ++i) {
            const int row = 2 * i + hi;
            f32x4 sc;
            #pragma unroll
            for (int j = 0; j < 4; ++j) sc[j] = av[i][j] * rv8[i];
            *(f32x4*)(attnp + ((size_t)bh * SEQ + qbase + row) * SEQ
                      + k0 + c * CH + 4 * cl) = sc;
            u32x2 w;
            w[0] = pkt(sc[0], sc[1]);
            w[1] = pkt(sc[2], sc[3]);
            *(u32x2*)(pw + row * PSTR + 4 * cl) = w;
        }
    };
    auto frag = [&](int c, VS& SA, VS& SB) {
        #pragma unroll
        for (int s = 0; s < NSUB; ++s) {
            const int tk = 4 * c + s;
            VS& S = (s & 1) ? SB : SA;
            union { bf16x8 v; unsigned int u[4]; } vf[4];
            #pragma unroll
            for (int nb = 0; nb < 4; ++nb)
                #pragma unroll
                for (int i = 0; i < 4; ++i)
                    vf[nb].u[i] = pkt(S.v[nb][2 * i], S.v[nb][2 * i + 1]);
            bf16x8 pf = *(const bf16x8*)(pw + l15 * PSTR + s * KT + 8 * g);
            __builtin_amdgcn_s_setprio(1);
            #pragma unroll
            for (int nb = 0; nb < 4; ++nb)
                accO[nb] = __builtin_amdgcn_mfma_f32_16x16x32_bf16(pf, vf[nb].v, accO[nb], 0, 0, 0);
            __builtin_amdgcn_s_setprio(0);
            load_v((tk + 2) & 31, S);
        }
    };

    {
        VS VA, VB;
        f32x4 avA[8], avB[8];
        load_v(0, VA);
        load_v(1, VB);
        load_av(0, avA);
        for (int c = 0; c < NCH; c += 2) {
            load_av(c + 1, avB);
            consume_av(c, avA);
            frag(c, VA, VB);
            if (c + 2 < NCH) load_av(c + 2, avA);
            consume_av(c + 1, avB);
            frag(c + 1, VA, VB);
        }
    }

    if (wid == 1) {
        #pragma unroll
        for (int rr = 0; rr < 4; ++rr)
            #pragma unroll
            for (int nb = 0; nb < 4; ++nb)
                OA[4 * g + rr][16 * nb + l15] = accO[nb][rr];
    }
    __syncthreads();

    if (wid == 0) {
        float* outBase = outp + ((size_t)bh * SEQ + qbase) * DH;
        #pragma unroll
        for (int rr = 0; rr < 4; ++rr)
            #pragma unroll
            for (int nb = 0; nb < 4; ++nb)
                outBase[(4 * g + rr) * DH + 16 * nb + l15] =
                    accO[nb][rr] + OA[4 * g + rr][16 * nb + l15];
    }
}

extern "C" void kernel_launch(void* const* d_in, const int* in_sizes, int n_in,
                              void* d_out, int out_size, void* d_ws, size_t ws_size,
                              hipStream_t stream) {
    const float* qp = (const float*)d_in[0];
    const float* kp = (const float*)d_in[1];
    const float* vp = (const float*)d_in[2];
    const void*  mp = d_in[3];
    const float* bp = (const float*)d_in[4];

    float* outp  = (float*)d_out;
    float* attnp = outp + (size_t)BATCH * NH * SEQ * DH;   // out first, then attn (f32)
    float* lsump = (float*)d_ws;                            // 256 KB scratch

    hipMemsetAsync(lsump, 0, (size_t)BATCH * NH * SEQ * sizeof(float), stream);

    dim3 grid(4096), block(128);
    // mask layout resolved on-device; mismatched instantiation exits immediately
    sdpa_score<true ><<<grid, block, 0, stream>>>(qp, kp, mp, bp, attnp, lsump);
    sdpa_score<false><<<grid, block, 0, stream>>>(qp, kp, mp, bp, attnp, lsump);

    sdpa_pv<<<grid, block, 0, stream>>>(vp, attnp, lsump, outp);
}

// Round 16
// 929.051 us; speedup vs baseline: 1.3048x; 1.3048x over previous
//
#include <hip/hip_runtime.h>

#define BATCH 2
#define NH    16
#define SEQ   2048
#define DH    64
#define KT    32
#define KHALF (SEQ / 2)
#define CH    128              // chunk columns (contiguity unit = 512B/row)
#define NCH   (KHALF / CH)     // 8 chunks per k-half
#define NSUB  (CH / KT)        // 4 MFMA sub-tiles per chunk
#define SSTR  132              // score LDS row stride in dwords (128+4 pad)
#define PSTR  136              // pv LDS row stride in bf16 elems

typedef __attribute__((ext_vector_type(8))) short          bf16x8;
typedef __attribute__((ext_vector_type(4))) float          f32x4;
typedef __attribute__((ext_vector_type(2))) unsigned int   u32x2;
typedef __attribute__((ext_vector_type(4))) int            i32x4;

__device__ __forceinline__ unsigned short f2bf(float f) {   // RNE (Q only)
    union { float f; unsigned int i; } c;
    c.f = f;
    unsigned int x = c.i;
    x += 0x7fffu + ((x >> 16) & 1u);
    return (unsigned short)(x >> 16);
}
__device__ __forceinline__ unsigned int pkt(float lo, float hi) {   // trunc bf16 pair
    union { float f; unsigned int u; } a, b;
    a.f = lo; b.f = hi;
    return (b.u & 0xFFFF0000u) | (a.u >> 16);
}

// ============ kernel 1: scores, LDS pivot + slim bias-only double-buffer ============
template<bool ISBYTE>
__global__ __launch_bounds__(128, 2)
void sdpa_score(const float* __restrict__ qp,
                const float* __restrict__ kp,
                const void*  __restrict__ mp,
                const float* __restrict__ bp,
                float* __restrict__ attnp,
                float* __restrict__ lsump)
{
    __shared__ __align__(16) float S_lds[2][16 * SSTR];   // raw-score chunk per wave

    const int tid  = threadIdx.x;
    const int wid  = tid >> 6;          // k-half
    const int lane = tid & 63;
    const int l15  = lane & 15;         // q (fragment layout)
    const int g    = lane >> 4;
    const int cl   = lane & 31;         // consume: col-lane (16B granule)
    const int hi   = lane >> 5;         // consume: row parity

    const unsigned int* mw = (const unsigned int*)mp;
    if ((__any((int)(mw[lane & 31] > 1u)) != 0) != ISBYTE) return;

    const int bid  = blockIdx.x;
    const int orig = (bid & 7) * 512 + (bid >> 3);   // bijective XCD swizzle
    const int h    = orig >> 8;
    const int rem  = orig & 255;
    const int qt   = rem >> 1;
    const int b    = rem & 1;                        // b-pair adjacent -> bias L2 share
    const int bh   = b * NH + h;
    const int qbase = qt * 16;
    const int k0   = wid * KHALF;

    const float* kbh = kp + (size_t)bh * SEQ * DH;
    float* sw = &S_lds[wid][0];

    bf16x8 qf0, qf1;
    {
        const float* qb = qp + ((size_t)bh * SEQ + qbase + l15) * DH + g * 8;
        #pragma unroll
        for (int j = 0; j < 8; ++j) {
            qf0[j] = (short)f2bf(qb[j]      * 0.125f);
            qf1[j] = (short)f2bf(qb[32 + j] * 0.125f);
        }
    }

    struct KS { f32x4 k[2][4]; };
    auto load_k = [&](int tk, KS& R) {               // tk = sub-tile idx in k-half
        const int kb = k0 + tk * KT;
        #pragma unroll
        for (int mb = 0; mb < 2; ++mb) {
            const float* arow = kbh + (size_t)(kb + 16 * mb + l15) * DH + g * 8;
            R.k[mb][0] = *(const f32x4*)(arow);
            R.k[mb][1] = *(const f32x4*)(arow + 4);
            R.k[mb][2] = *(const f32x4*)(arow + 32);
            R.k[mb][3] = *(const f32x4*)(arow + 36);
        }
    };

    auto produce = [&](const KS& R, int ko) {        // ko = col offset in chunk
        #pragma unroll
        for (int mb = 0; mb < 2; ++mb) {
            union { bf16x8 v; unsigned int u[4]; } A0, A1;
            A0.u[0] = pkt(R.k[mb][0][0], R.k[mb][0][1]);
            A0.u[1] = pkt(R.k[mb][0][2], R.k[mb][0][3]);
            A0.u[2] = pkt(R.k[mb][1][0], R.k[mb][1][1]);
            A0.u[3] = pkt(R.k[mb][1][2], R.k[mb][1][3]);
            A1.u[0] = pkt(R.k[mb][2][0], R.k[mb][2][1]);
            A1.u[1] = pkt(R.k[mb][2][2], R.k[mb][2][3]);
            A1.u[2] = pkt(R.k[mb][3][0], R.k[mb][3][1]);
            A1.u[3] = pkt(R.k[mb][3][2], R.k[mb][3][3]);
            f32x4 c = (f32x4){0.f, 0.f, 0.f, 0.f};
            __builtin_amdgcn_s_setprio(1);
            c = __builtin_amdgcn_mfma_f32_16x16x32_bf16(A0.v, qf0, c, 0, 0, 0);
            c = __builtin_amdgcn_mfma_f32_16x16x32_bf16(A1.v, qf1, c, 0, 0, 0);
            __builtin_amdgcn_s_setprio(0);
            *(f32x4*)(sw + l15 * SSTR + ko + 16 * mb + 4 * g) = c;
        }
    };

    // bias-only prefetch buffer (32 VGPR each; the ONLY HBM-latency input stream)
    auto load_bias = [&](int c, f32x4* B) {          // contiguous: 2 rows x 512B per instr
        const int colbase = k0 + c * CH;
        #pragma unroll
        for (int i = 0; i < 8; ++i)
            B[i] = *(const f32x4*)(bp + ((size_t)h * SEQ + qbase + 2 * i + hi) * SEQ
                                   + colbase + 4 * cl);
    };

    float rs[8];
    #pragma unroll
    for (int i = 0; i < 8; ++i) rs[i] = 0.0f;

    // consume: mask loaded here (L2-resident: [B,1,S,S] shared by 16 heads), short-lived regs
    auto consume = [&](int c, const f32x4* B) {
        const int colbase = k0 + c * CH;
        unsigned int m8[8];
        i32x4 mi[8];
        #pragma unroll
        for (int i = 0; i < 8; ++i) {
            const int row = qbase + 2 * i + hi;
            if constexpr (ISBYTE)
                m8[i] = *(const unsigned int*)((const unsigned char*)mp +
                         ((size_t)b * SEQ + row) * SEQ + colbase + 4 * cl);
            else
                mi[i] = *(const i32x4*)((const int*)mp +
                         ((size_t)b * SEQ + row) * SEQ + colbase + 4 * cl);
        }
        #pragma unroll
        for (int i = 0; i < 8; ++i) {
            const int row = 2 * i + hi;
            f32x4 p = *(const f32x4*)(sw + row * SSTR + 4 * cl);
            f32x4 pa;
            #pragma unroll
            for (int j = 0; j < 4; ++j) {
                const float s = p[j] + B[i][j];
                int m;
                if constexpr (ISBYTE) m = (int)((m8[i] >> (8 * j)) & 0xFFu);
                else                  m = mi[i][j];
                pa[j] = m ? 0.0f : __expf(s);
            }
            rs[i] += pa[0] + pa[1] + pa[2] + pa[3];   // lane-local; reduce deferred
            *(f32x4*)(attnp + ((size_t)bh * SEQ + qbase + row) * SEQ + colbase + 4 * cl) = pa;
        }
    };

    KS RA, RB;
    load_k(0, RA);
    load_k(1, RB);

    auto produce_chunk = [&](int c) {
        #pragma unroll
        for (int s = 0; s < NSUB; ++s) {
            const int tk = 4 * c + s;
            if ((s & 1) == 0) { produce(RA, s * KT); load_k((tk + 2) & 31, RA); }
            else              { produce(RB, s * KT); load_k((tk + 2) & 31, RB); }
        }
    };

    {
        f32x4 BA[8], BB[8];
        load_bias(0, BA);                            // prologue
        for (int c = 0; c < NCH; c += 2) {
            load_bias(c + 1, BB);                    // next chunk's bias issued early
            produce_chunk(c);
            consume(c, BA);                          // BA issued >= 1 full iter ago
            load_bias((c + 2) & (NCH - 1), BA);      // ring (last wraps harmlessly)
            produce_chunk(c + 1);
            consume(c + 1, BB);
        }
    }

    // deferred row-sum reduce: 5-level tree once per row, then 2 atomics/row total
    #pragma unroll
    for (int i = 0; i < 8; ++i) {
        float t = rs[i];
        t += __shfl_xor(t, 1, 64);
        t += __shfl_xor(t, 2, 64);
        t += __shfl_xor(t, 4, 64);
        t += __shfl_xor(t, 8, 64);
        t += __shfl_xor(t, 16, 64);
        rs[i] = t;
    }
    if (cl == 0) {
        #pragma unroll
        for (int i = 0; i < 8; ++i)
            atomicAdd(&lsump[(size_t)bh * SEQ + qbase + 2 * i + hi], rs[i]);
    }
}

// ============ kernel 2: normalize attn (contiguous R/W) + out = P_norm . V ============
__global__ __launch_bounds__(128, 2)
void sdpa_pv(const float* __restrict__ vp,
             float* __restrict__ attnp,
             const float* __restrict__ lsump,
             float* __restrict__ outp)
{
    __shared__ __align__(16) unsigned short P_lds[2][16 * PSTR];
    __shared__ float OA[16][65];

    const int tid  = threadIdx.x;
    const int wid  = tid >> 6;
    const int lane = tid & 63;
    const int l15  = lane & 15;
    const int g    = lane >> 4;
    const int cl   = lane & 31;
    const int hi   = lane >> 5;

    const int bid  = blockIdx.x;
    const int orig = (bid & 7) * 512 + (bid >> 3);
    const int bh   = orig >> 7;                      // 4 bh per XCD -> V fits L2
    const int qt   = orig & 127;
    const int qbase = qt * 16;
    const int k0   = wid * KHALF;

    float rv8[8];
    #pragma unroll
    for (int i = 0; i < 8; ++i)
        rv8[i] = 1.0f / lsump[(size_t)bh * SEQ + qbase + 2 * i + hi];

    const float* vbh = vp + (size_t)bh * SEQ * DH + (size_t)k0 * DH;
    unsigned short* pw = &P_lds[wid][0];

    f32x4 accO[4];
    #pragma unroll
    for (int i = 0; i < 4; ++i) accO[i] = (f32x4){0.f, 0.f, 0.f, 0.f};

    struct VS { float v[4][8]; };
    auto load_v = [&](int tk, VS& S) {
        const float* vb2 = vbh + (size_t)tk * KT * DH + 512 * g + l15;
        #pragma unroll
        for (int nb = 0; nb < 4; ++nb)
            #pragma unroll
            for (int j = 0; j < 8; ++j)
                S.v[nb][j] = vb2[j * 64 + 16 * nb];
    };

    auto load_av = [&](int c, f32x4* av) {
        #pragma unroll
        for (int i = 0; i < 8; ++i)
            av[i] = *(const f32x4*)(attnp + ((size_t)bh * SEQ + qbase + 2 * i + hi) * SEQ
                                    + k0 + c * CH + 4 * cl);
    };
    auto consume_av = [&](int c, const f32x4* av) {
        #pragma unroll
        for (int i = 0; i < 8; ++i) {
            const int row = 2 * i + hi;
            f32x4 sc;
            #pragma unroll
            for (int j = 0; j < 4; ++j) sc[j] = av[i][j] * rv8[i];
            *(f32x4*)(attnp + ((size_t)bh * SEQ + qbase + row) * SEQ
                      + k0 + c * CH + 4 * cl) = sc;
            u32x2 w;
            w[0] = pkt(sc[0], sc[1]);
            w[1] = pkt(sc[2], sc[3]);
            *(u32x2*)(pw + row * PSTR + 4 * cl) = w;
        }
    };
    auto frag = [&](int c, VS& SA, VS& SB) {
        #pragma unroll
        for (int s = 0; s < NSUB; ++s) {
            const int tk = 4 * c + s;
            VS& S = (s & 1) ? SB : SA;
            union { bf16x8 v; unsigned int u[4]; } vf[4];
            #pragma unroll
            for (int nb = 0; nb < 4; ++nb)
                #pragma unroll
                for (int i = 0; i < 4; ++i)
                    vf[nb].u[i] = pkt(S.v[nb][2 * i], S.v[nb][2 * i + 1]);
            bf16x8 pf = *(const bf16x8*)(pw + l15 * PSTR + s * KT + 8 * g);
            __builtin_amdgcn_s_setprio(1);
            #pragma unroll
            for (int nb = 0; nb < 4; ++nb)
                accO[nb] = __builtin_amdgcn_mfma_f32_16x16x32_bf16(pf, vf[nb].v, accO[nb], 0, 0, 0);
            __builtin_amdgcn_s_setprio(0);
            load_v((tk + 2) & 31, S);
        }
    };

    {
        VS VA, VB;
        f32x4 avA[8], avB[8];
        load_v(0, VA);
        load_v(1, VB);
        load_av(0, avA);
        for (int c = 0; c < NCH; c += 2) {
            load_av(c + 1, avB);
            consume_av(c, avA);
            frag(c, VA, VB);
            if (c + 2 < NCH) load_av(c + 2, avA);
            consume_av(c + 1, avB);
            frag(c + 1, VA, VB);
        }
    }

    if (wid == 1) {
        #pragma unroll
        for (int rr = 0; rr < 4; ++rr)
            #pragma unroll
            for (int nb = 0; nb < 4; ++nb)
                OA[4 * g + rr][16 * nb + l15] = accO[nb][rr];
    }
    __syncthreads();

    if (wid == 0) {
        float* outBase = outp + ((size_t)bh * SEQ + qbase) * DH;
        #pragma unroll
        for (int rr = 0; rr < 4; ++rr)
            #pragma unroll
            for (int nb = 0; nb < 4; ++nb)
                outBase[(4 * g + rr) * DH + 16 * nb + l15] =
                    accO[nb][rr] + OA[4 * g + rr][16 * nb + l15];
    }
}

extern "C" void kernel_launch(void* const* d_in, const int* in_sizes, int n_in,
                              void* d_out, int out_size, void* d_ws, size_t ws_size,
                              hipStream_t stream) {
    const float* qp = (const float*)d_in[0];
    const float* kp = (const float*)d_in[1];
    const float* vp = (const float*)d_in[2];
    const void*  mp = d_in[3];
    const float* bp = (const float*)d_in[4];

    float* outp  = (float*)d_out;
    float* attnp = outp + (size_t)BATCH * NH * SEQ * DH;   // out first, then attn (f32)
    float* lsump = (float*)d_ws;                            // 256 KB scratch

    hipMemsetAsync(lsump, 0, (size_t)BATCH * NH * SEQ * sizeof(float), stream);

    dim3 grid(4096), block(128);
    // mask layout resolved on-device; mismatched instantiation exits immediately
    sdpa_score<true ><<<grid, block, 0, stream>>>(qp, kp, mp, bp, attnp, lsump);
    sdpa_score<false><<<grid, block, 0, stream>>>(qp, kp, mp, bp, attnp, lsump);

    sdpa_pv<<<grid, block, 0, stream>>>(vp, attnp, lsump, outp);
}

// Round 17
// 551.314 us; speedup vs baseline: 2.1987x; 1.6852x over previous
//
#include <hip/hip_runtime.h>

#define BATCH 2
#define NH    16
#define SEQ   2048
#define DH    64
#define NW    8             // waves per block
#define KSPAN 256           // k-cols per wave
#define CHUNK 64            // k-cols per chunk
#define NCHK  (KSPAN/CHUNK) // 4 chunks per wave
#define SUBT  32            // MFMA subtile cols

typedef __attribute__((ext_vector_type(8))) short          bf16x8;
typedef __attribute__((ext_vector_type(4))) float          f32x4;
typedef __attribute__((ext_vector_type(2))) unsigned int   u32x2;
typedef __attribute__((ext_vector_type(4))) int            i32x4;

__device__ __forceinline__ unsigned short f2bf(float f) {   // RNE (Q only)
    union { float f; unsigned int i; } c;
    c.f = f;
    unsigned int x = c.i;
    x += 0x7fffu + ((x >> 16) & 1u);
    return (unsigned short)(x >> 16);
}
__device__ __forceinline__ unsigned int pkt(float lo, float hi) {   // trunc bf16 pair
    union { float f; unsigned int u; } a, b;
    a.f = lo; b.f = hi;
    return (b.u & 0xFFFF0000u) | (a.u >> 16);
}
__device__ __forceinline__ float bfu2f(unsigned short u) {
    union { unsigned int i; float f; } c;
    c.i = ((unsigned int)u) << 16;
    return c.f;
}

// Single-pass SDPA: P held in LDS (bf16) until row-sums complete; attn written once.
template<bool ISBYTE>
__global__ __launch_bounds__(512, 2)
void sdpa_fused(const float* __restrict__ qp,
                const float* __restrict__ kp,
                const float* __restrict__ vp,
                const void*  __restrict__ mp,
                const float* __restrict__ bp,
                float* __restrict__ outp,
                float* __restrict__ attnp)
{
    // Pbig[row 0..15][k 0..2047] bf16, row stride 4096B, XOR-swizzled (^((row&7)<<4))
    __shared__ __align__(16) unsigned short Pbig[16 * 2048];          // 64 KB
    // Arena[w]: phase1 = raw-score pivot (16x64 f32, XOR-swz); end = accO deposit (16x64 f32)
    __shared__ __align__(16) float Arena[NW][16 * CHUNK];             // 32 KB
    __shared__ float Lsum[NW][16];                                    // row-sum partials

    const int tid  = threadIdx.x;
    const int w    = tid >> 6;          // wave id: owns k in [256w, 256w+256)
    const int lane = tid & 63;
    const int l15  = lane & 15;
    const int g    = lane >> 4;

    // mask layout probe — block-uniform exit BEFORE any barrier
    const unsigned int* mw = (const unsigned int*)mp;
    if ((__any((int)(mw[lane & 31] > 1u)) != 0) != ISBYTE) return;

    const int bid  = blockIdx.x;
    const int orig = (bid & 7) * 512 + (bid >> 3);   // bijective XCD swizzle (4096 blocks)
    const int h    = orig >> 8;                      // 2 heads per XCD
    const int rem  = orig & 255;
    const int qt   = rem >> 1;
    const int b    = rem & 1;                        // b-pair adjacent -> bias L2 share
    const int bh   = b * NH + h;
    const int qbase = qt * 16;
    const int kw   = w * KSPAN;

    const float* kbh = kp + (size_t)bh * SEQ * DH;
    const float* vbh = vp + (size_t)bh * SEQ * DH;
    char* pivot = (char*)&Arena[w][0];
    char* pbig  = (char*)Pbig;

    // Q fragment (B-operand of swapped QK^T), prescaled by 1/8
    bf16x8 qf0, qf1;
    {
        const float* qb = qp + ((size_t)bh * SEQ + qbase + l15) * DH + g * 8;
        #pragma unroll
        for (int j = 0; j < 8; ++j) {
            qf0[j] = (short)f2bf(qb[j]      * 0.125f);
            qf1[j] = (short)f2bf(qb[32 + j] * 0.125f);
        }
    }

    struct KS { f32x4 k[2][4]; };
    auto load_k = [&](int tk, KS& R) {               // tk = subtile idx 0..7 in wave span
        const int kb = kw + tk * SUBT;
        #pragma unroll
        for (int mb = 0; mb < 2; ++mb) {
            const float* arow = kbh + (size_t)(kb + 16 * mb + l15) * DH + g * 8;
            R.k[mb][0] = *(const f32x4*)(arow);
            R.k[mb][1] = *(const f32x4*)(arow + 4);
            R.k[mb][2] = *(const f32x4*)(arow + 32);
            R.k[mb][3] = *(const f32x4*)(arow + 36);
        }
    };

    auto produce = [&](const KS& R, int s2) {        // s2 = subtile within chunk (0/1)
        #pragma unroll
        for (int mb = 0; mb < 2; ++mb) {
            union { bf16x8 v; unsigned int u[4]; } A0, A1;
            A0.u[0] = pkt(R.k[mb][0][0], R.k[mb][0][1]);
            A0.u[1] = pkt(R.k[mb][0][2], R.k[mb][0][3]);
            A0.u[2] = pkt(R.k[mb][1][0], R.k[mb][1][1]);
            A0.u[3] = pkt(R.k[mb][1][2], R.k[mb][1][3]);
            A1.u[0] = pkt(R.k[mb][2][0], R.k[mb][2][1]);
            A1.u[1] = pkt(R.k[mb][2][2], R.k[mb][2][3]);
            A1.u[2] = pkt(R.k[mb][3][0], R.k[mb][3][1]);
            A1.u[3] = pkt(R.k[mb][3][2], R.k[mb][3][3]);
            f32x4 c = (f32x4){0.f, 0.f, 0.f, 0.f};
            __builtin_amdgcn_s_setprio(1);
            c = __builtin_amdgcn_mfma_f32_16x16x32_bf16(A0.v, qf0, c, 0, 0, 0);
            c = __builtin_amdgcn_mfma_f32_16x16x32_bf16(A1.v, qf1, c, 0, 0, 0);
            __builtin_amdgcn_s_setprio(0);
            // raw scores -> pivot [q=l15][col = 32*s2+16*mb+4*g .. +3], XOR-swizzled
            const int byo = (128 * s2 + 64 * mb + 16 * g) ^ ((l15 & 7) << 4);
            *(f32x4*)(pivot + l15 * 256 + byo) = c;
        }
    };

    auto load_bias = [&](int c, f32x4* B) {          // contiguous: 4 rows x 256B per instr
        #pragma unroll
        for (int i = 0; i < 4; ++i)
            B[i] = *(const f32x4*)(bp + ((size_t)h * SEQ + qbase + 4 * i + g) * SEQ
                                   + kw + c * CHUNK + 4 * l15);
    };

    float rs[4] = {0.f, 0.f, 0.f, 0.f};              // row partials (row = 4i+g)

    auto consume = [&](int c, const f32x4* B) {
        #pragma unroll
        for (int i = 0; i < 4; ++i) {
            const int qr = 4 * i + g;                // local row
            // mask (L2/L3-resident; loaded at use)
            int m4[4];
            if constexpr (ISBYTE) {
                unsigned int mk = *(const unsigned int*)((const unsigned char*)mp +
                    ((size_t)b * SEQ + qbase + qr) * SEQ + kw + c * CHUNK + 4 * l15);
                #pragma unroll
                for (int j = 0; j < 4; ++j) m4[j] = (int)((mk >> (8 * j)) & 0xFFu);
            } else {
                i32x4 mk = *(const i32x4*)((const int*)mp +
                    ((size_t)b * SEQ + qbase + qr) * SEQ + kw + c * CHUNK + 4 * l15);
                #pragma unroll
                for (int j = 0; j < 4; ++j) m4[j] = mk[j];
            }
            // raw scores from pivot (contiguous read, XOR)
            f32x4 p = *(const f32x4*)(pivot + qr * 256 + ((16 * l15) ^ ((qr & 7) << 4)));
            f32x4 pa;
            #pragma unroll
            for (int j = 0; j < 4; ++j)
                pa[j] = m4[j] ? 0.0f : __expf(p[j] + B[i][j]);
            rs[i] += pa[0] + pa[1] + pa[2] + pa[3];
            // stash UNNORMALIZED P (bf16) into persistent span
            u32x2 pw;
            pw[0] = pkt(pa[0], pa[1]);
            pw[1] = pkt(pa[2], pa[3]);
            const int byo = (2 * kw + 128 * c + 8 * l15) ^ ((qr & 7) << 4);
            *(u32x2*)(pbig + qr * 4096 + byo) = pw;
        }
    };

    f32x4 accO[4];   // accO[nb][rr] = O[q=qbase+4g+rr][d=16nb+l15] (this wave's k-span)
    #pragma unroll
    for (int i = 0; i < 4; ++i) accO[i] = (f32x4){0.f, 0.f, 0.f, 0.f};

    auto pv = [&](int c) {
        #pragma unroll
        for (int ks2 = 0; ks2 < 2; ++ks2) {
            const int colg = kw + (2 * c + ks2) * SUBT;
            // A-frag: P[q=l15][k=colg+8g .. +7] from Pbig (XOR; 16B-aligned)
            const int byo = (2 * colg + 16 * g) ^ ((l15 & 7) << 4);
            bf16x8 pf = *(const bf16x8*)(pbig + l15 * 4096 + byo);
            // B-frag: V[colg+8g+j][16nb+l15] direct from global (L2)
            const float* vb2 = vbh + (size_t)colg * DH + 512 * g + l15;
            union { bf16x8 v; unsigned int u[4]; } vf[4];
            #pragma unroll
            for (int nb = 0; nb < 4; ++nb)
                #pragma unroll
                for (int i2 = 0; i2 < 4; ++i2)
                    vf[nb].u[i2] = pkt(vb2[(2 * i2) * 64 + 16 * nb],
                                       vb2[(2 * i2 + 1) * 64 + 16 * nb]);
            __builtin_amdgcn_s_setprio(1);
            #pragma unroll
            for (int nb = 0; nb < 4; ++nb)
                accO[nb] = __builtin_amdgcn_mfma_f32_16x16x32_bf16(pf, vf[nb].v, accO[nb], 0, 0, 0);
            __builtin_amdgcn_s_setprio(0);
        }
    };

    // ================= phase 1: 4 chunks, bias D=1-ahead, K D=2 ring =================
    {
        KS RA, RB;
        f32x4 BA[4], BB[4];
        load_k(0, RA);
        load_k(1, RB);
        load_bias(0, BA);

        #pragma unroll
        for (int c = 0; c < NCHK; ++c) {
            f32x4* Bcur = (c & 1) ? BB : BA;
            f32x4* Bnxt = (c & 1) ? BA : BB;
            if (c < NCHK - 1) load_bias(c + 1, Bnxt);
            produce(RA, 0);  load_k((2 * c + 2) & 7, RA);
            produce(RB, 1);  load_k((2 * c + 3) & 7, RB);
            consume(c, Bcur);
            pv(c);
        }
    }

    // row-sum partials -> Lsum; accO -> Arena (unions the now-dead pivot)
    #pragma unroll
    for (int i = 0; i < 4; ++i) {
        float t = rs[i];
        t += __shfl_xor(t, 1, 64);
        t += __shfl_xor(t, 2, 64);
        t += __shfl_xor(t, 4, 64);
        t += __shfl_xor(t, 8, 64);
        if (l15 == 0) Lsum[w][4 * i + g] = t;
    }
    #pragma unroll
    for (int rr = 0; rr < 4; ++rr)
        #pragma unroll
        for (int nb = 0; nb < 4; ++nb)
            Arena[w][(4 * g + rr) * 64 + 16 * nb + l15] = accO[nb][rr];

    __syncthreads();

    // ================= phase 2: normalize own span, write attn ONCE =================
    float rv[4];
    #pragma unroll
    for (int i = 0; i < 4; ++i) {
        float s = 0.f;
        #pragma unroll
        for (int ww = 0; ww < NW; ++ww) s += Lsum[ww][4 * i + g];
        rv[i] = 1.0f / s;
    }

    #pragma unroll
    for (int i = 0; i < 4; ++i) {
        const int qr = 4 * i + g;
        #pragma unroll
        for (int u = 0; u < 2; ++u) {
            const int byo = (2 * kw + 256 * u + 16 * l15) ^ ((qr & 7) << 4);
            bf16x8 pb8 = *(const bf16x8*)(pbig + qr * 4096 + byo);
            f32x4 o0, o1;
            #pragma unroll
            for (int j = 0; j < 4; ++j) {
                o0[j] = bfu2f((unsigned short)pb8[j])     * rv[i];
                o1[j] = bfu2f((unsigned short)pb8[4 + j]) * rv[i];
            }
            float* ap = attnp + ((size_t)bh * SEQ + qbase + qr) * SEQ
                        + kw + u * 128 + 8 * l15;
            *(f32x4*)ap       = o0;
            *(f32x4*)(ap + 4) = o1;
        }
    }

    // out: wave 0 combines the 8 deposits + normalizes
    if (w == 0) {
        const int d = lane;                          // 0..63
        #pragma unroll
        for (int r = 0; r < 16; ++r) {
            float s = 0.f, o = 0.f;
            #pragma unroll
            for (int ww = 0; ww < NW; ++ww) {
                s += Lsum[ww][r];
                o += Arena[ww][r * 64 + d];
            }
            outp[((size_t)bh * SEQ + qbase + r) * DH + d] = o / s;
        }
    }
}

extern "C" void kernel_launch(void* const* d_in, const int* in_sizes, int n_in,
                              void* d_out, int out_size, void* d_ws, size_t ws_size,
                              hipStream_t stream) {
    const float* qp = (const float*)d_in[0];
    const float* kp = (const float*)d_in[1];
    const float* vp = (const float*)d_in[2];
    const void*  mp = d_in[3];
    const float* bp = (const float*)d_in[4];

    float* outp  = (float*)d_out;
    float* attnp = outp + (size_t)BATCH * NH * SEQ * DH;   // out first, then attn (f32)

    dim3 grid(BATCH * NH * (SEQ / 16)), block(512);
    // mask layout resolved on-device; mismatched instantiation exits immediately
    sdpa_fused<true ><<<grid, block, 0, stream>>>(qp, kp, vp, mp, bp, outp, attnp);
    sdpa_fused<false><<<grid, block, 0, stream>>>(qp, kp, vp, mp, bp, outp, attnp);
}